// Round 1
// baseline (2716.150 us; speedup 1.0000x reference)
//
#include <hip/hip_runtime.h>

#define N_NODES 10000
#define N_EDGES 160000
#define N_TRI   1600000
#define DM      256
#define CH      64
#define HH      1024

// ---------------------------------------------------------------- projections
__global__ __launch_bounds__(256) void k_node_proj(
    const float* __restrict__ x, const float* __restrict__ Ws, const float* __restrict__ bs,
    const float* __restrict__ Wd, const float* __restrict__ bd,
    float* __restrict__ xs, float* __restrict__ xd) {
  __shared__ float xl[4][DM];
  int tid = threadIdx.x;
  int n0 = blockIdx.x * 4;
  for (int i = tid; i < 4 * DM; i += 256) xl[i >> 8][i & 255] = x[n0 * DM + i];
  __syncthreads();
  int c = tid & 63, g = tid >> 6;
  float as = bs[c], ad = bd[c];
  for (int d = 0; d < DM; d++) {
    float xv = xl[g][d];
    as += xv * Ws[d * CH + c];
    ad += xv * Wd[d * CH + c];
  }
  int n = n0 + g;
  xs[n * CH + c] = as;
  xd[n * CH + c] = ad;
}

// ye = y@W_edge + b_edge, fused with gather-add -> xij
__global__ __launch_bounds__(256) void k_edge_proj(
    const float* __restrict__ y, const float* __restrict__ We, const float* __restrict__ be,
    const float* __restrict__ xs, const float* __restrict__ xd,
    const int* __restrict__ src, const int* __restrict__ dst,
    float* __restrict__ xij) {
  __shared__ float yl[16][DM];
  int tid = threadIdx.x;
  int e0 = blockIdx.x * 16;
  for (int i = tid; i < 16 * DM; i += 256) yl[i >> 8][i & 255] = y[e0 * DM + i];
  __syncthreads();
  int c = tid & 63, g = tid >> 6;
  float acc[4];
#pragma unroll
  for (int s = 0; s < 4; s++) acc[s] = be[c];
  for (int d = 0; d < DM; d += 4) {
    float w0 = We[(d + 0) * CH + c];
    float w1 = We[(d + 1) * CH + c];
    float w2 = We[(d + 2) * CH + c];
    float w3 = We[(d + 3) * CH + c];
#pragma unroll
    for (int s = 0; s < 4; s++) {
      const float4 yv = *(const float4*)&yl[g * 4 + s][d];
      acc[s] += yv.x * w0 + yv.y * w1 + yv.z * w2 + yv.w * w3;
    }
  }
#pragma unroll
  for (int s = 0; s < 4; s++) {
    int e = e0 + g * 4 + s;
    xij[e * CH + c] = acc[s] + xs[src[e] * CH + c] + xd[dst[e] * CH + c];
  }
}

// ---------------------------------------------------------------- rnorm
__global__ void k_rnorm(const float* __restrict__ r, float* __restrict__ rn) {
  int e = blockIdx.x * 256 + threadIdx.x;
  if (e >= N_EDGES) return;
  float a = r[e * 3 + 0], b = r[e * 3 + 1], c = r[e * 3 + 2];
  float inv = rsqrtf(a * a + b * b + c * c);
  rn[e * 3 + 0] = -a * inv;
  rn[e * 3 + 1] = -b * inv;
  rn[e * 3 + 2] = -c * inv;
}

// ---------------------------------------------------------------- counting sort by tdst
__global__ void k_hist(const int* __restrict__ tdst, int* __restrict__ cnt) {
  int t = blockIdx.x * 256 + threadIdx.x;
  if (t < N_TRI) atomicAdd(&cnt[tdst[t]], 1);
}

__global__ __launch_bounds__(256) void k_scan_sum(const int* __restrict__ cnt,
                                                  int* __restrict__ bsum, int n) {
  __shared__ int s[256];
  int b = blockIdx.x, tid = threadIdx.x;
  int tot = 0;
#pragma unroll
  for (int i = 0; i < 8; i++) {
    int idx = b * 2048 + i * 256 + tid;
    if (idx < n) tot += cnt[idx];
  }
  s[tid] = tot;
  __syncthreads();
  for (int off = 128; off > 0; off >>= 1) {
    if (tid < off) s[tid] += s[tid + off];
    __syncthreads();
  }
  if (tid == 0) bsum[b] = s[0];
}

__global__ void k_scan_top(int* __restrict__ bsum, int nb, int* __restrict__ start_last) {
  if (threadIdx.x == 0) {
    int run = 0;
    for (int i = 0; i < nb; i++) {
      int v = bsum[i];
      bsum[i] = run;
      run += v;
    }
    *start_last = run;  // == N_TRI
  }
}

__global__ __launch_bounds__(256) void k_scan_apply(const int* __restrict__ cnt,
                                                    const int* __restrict__ bsum,
                                                    int* __restrict__ start,
                                                    int* __restrict__ cur, int n) {
  __shared__ int s[256];
  int b = blockIdx.x, tid = threadIdx.x;
  int base = b * 2048 + tid * 8;
  int loc[8];
  int tot = 0;
#pragma unroll
  for (int i = 0; i < 8; i++) {
    int idx = base + i;
    int v = (idx < n) ? cnt[idx] : 0;
    loc[i] = tot;
    tot += v;
  }
  s[tid] = tot;
  __syncthreads();
  for (int off = 1; off < 256; off <<= 1) {
    int t2 = 0;
    if (tid >= off) t2 = s[tid - off];
    __syncthreads();
    if (tid >= off) s[tid] += t2;
    __syncthreads();
  }
  int excl = s[tid] - tot + bsum[b];
#pragma unroll
  for (int i = 0; i < 8; i++) {
    int idx = base + i;
    if (idx < n) {
      int v = excl + loc[i];
      start[idx] = v;
      cur[idx] = v;
    }
  }
}

__global__ void k_scatter(const int* __restrict__ tdst, int* __restrict__ cur,
                          int* __restrict__ sorted) {
  int t = blockIdx.x * 256 + threadIdx.x;
  if (t < N_TRI) {
    int p = atomicAdd(&cur[tdst[t]], 1);
    sorted[p] = t;
  }
}

// ---------------------------------------------------------------- triplet logits (one wave per triplet)
__global__ __launch_bounds__(256) void k_logits(
    const float* __restrict__ rn, const int* __restrict__ tsrc, const int* __restrict__ tdst,
    const float* __restrict__ xij, const float* __restrict__ attn,
    float* __restrict__ logits) {
  int tid = threadIdx.x;
  int t = blockIdx.x * 4 + (tid >> 6);
  int lane = tid & 63;
  int ts = tsrc[t], td = tdst[t];
  float ax = rn[ts * 3 + 0], ay = rn[ts * 3 + 1], az = rn[ts * 3 + 2];
  float bx = rn[td * 3 + 0], by = rn[td * 3 + 1], bz = rn[td * 3 + 2];
  float cosv = ax * bx + ay * by + az * bz;
  cosv = fminf(fmaxf(cosv, -1.0f + 1e-6f), 1.0f - 1e-6f);
  float theta = acosf(cosv);
  float z = __cosf(theta * (float)lane);
  float v = z + xij[ts * CH + lane] + xij[td * CH + lane];
  float sv = v / (1.0f + __expf(-v));
  float contrib = sv * attn[lane];
#pragma unroll
  for (int off = 32; off; off >>= 1) contrib += __shfl_xor(contrib, off);
  if (lane == 0) logits[t] = contrib;
}

// ---------------------------------------------------------------- segment softmax + weighted gather (one wave per edge)
__global__ __launch_bounds__(256) void k_softmax_ft(
    const int* __restrict__ start, const int* __restrict__ sorted,
    const float* __restrict__ logits, const int* __restrict__ tsrc,
    const float* __restrict__ xij, float* __restrict__ ft) {
  int tid = threadIdx.x;
  int e = blockIdx.x * 4 + (tid >> 6);
  int lane = tid & 63;
  int beg = start[e], end = start[e + 1];
  int deg = end - beg;
  float acc = 0.f;
  if (deg > 0) {
    if (deg <= 64) {
      int t = 0;
      float l = -1e30f;
      int ts_ = 0;
      if (lane < deg) {
        t = sorted[beg + lane];
        l = logits[t];
        ts_ = tsrc[t];
      }
      float mx = l;
#pragma unroll
      for (int off = 32; off; off >>= 1) mx = fmaxf(mx, __shfl_xor(mx, off));
      float ex = (lane < deg) ? __expf(l - mx) : 0.f;
      float den = ex;
#pragma unroll
      for (int off = 32; off; off >>= 1) den += __shfl_xor(den, off);
      float p = ex / den;
      for (int i = 0; i < deg; i++) {
        int tsi = __shfl(ts_, i);
        float ai = __shfl(p, i);
        acc += ai * xij[tsi * CH + lane];
      }
    } else {
      float mx = -1e30f;
      for (int i = lane; i < deg; i += 64) mx = fmaxf(mx, logits[sorted[beg + i]]);
#pragma unroll
      for (int off = 32; off; off >>= 1) mx = fmaxf(mx, __shfl_xor(mx, off));
      float den = 0.f;
      for (int i = lane; i < deg; i += 64) den += __expf(logits[sorted[beg + i]] - mx);
#pragma unroll
      for (int off = 32; off; off >>= 1) den += __shfl_xor(den, off);
      for (int i = 0; i < deg; i++) {
        int tt = sorted[beg + i];
        float ai = __expf(logits[tt] - mx) / den;
        acc += ai * xij[tsrc[tt] * CH + lane];
      }
    }
  }
  ft[e * CH + lane] = acc;
}

// ---------------------------------------------------------------- fused FFN: out = silu(ft@W1+b1)@W2 + b2
// M=32 edges per block; hidden computed in 4 chunks of 256 staged in LDS.
__global__ __launch_bounds__(256) void k_ffn(
    const float* __restrict__ ft, const float* __restrict__ W1, const float* __restrict__ b1,
    const float* __restrict__ W2, const float* __restrict__ b2, float* __restrict__ out) {
  __shared__ float ftl[32][CH];    // 8 KB
  __shared__ float hl[32][256];    // 32 KB
  int tid = threadIdx.x;
  int e0 = blockIdx.x * 32;
  for (int i = tid; i < 32 * CH; i += 256) ftl[i >> 6][i & 63] = ft[e0 * CH + i];

  // phase-2 thread tile: 4 edges (m) x 8 outputs (d)
  int td8 = tid & 31;
  int tmg = tid >> 5;   // 0..7
  int d0 = td8 * 8;
  int m2 = tmg * 4;
  float acc2[4][8];
#pragma unroll
  for (int i = 0; i < 4; i++)
#pragma unroll
    for (int j = 0; j < 8; j++) acc2[i][j] = b2[d0 + j];
  __syncthreads();

  // phase-1 thread tile: 8 edges (m) x 4 hidden (j)
  int tj = tid & 63;
  int tmg1 = tid >> 6;  // 0..3
  int m1 = tmg1 * 8;

  for (int cc = 0; cc < 4; cc++) {
    int j = cc * 256 + tj * 4;
    float a1[8][4];
#pragma unroll
    for (int i = 0; i < 8; i++)
#pragma unroll
      for (int q = 0; q < 4; q++) a1[i][q] = b1[j + q];
    for (int k = 0; k < CH; k++) {
      float4 w = *(const float4*)&W1[k * HH + j];
#pragma unroll
      for (int i = 0; i < 8; i++) {
        float fv = ftl[m1 + i][k];
        a1[i][0] += fv * w.x;
        a1[i][1] += fv * w.y;
        a1[i][2] += fv * w.z;
        a1[i][3] += fv * w.w;
      }
    }
#pragma unroll
    for (int i = 0; i < 8; i++) {
      float4 hv;
      hv.x = a1[i][0] / (1.f + __expf(-a1[i][0]));
      hv.y = a1[i][1] / (1.f + __expf(-a1[i][1]));
      hv.z = a1[i][2] / (1.f + __expf(-a1[i][2]));
      hv.w = a1[i][3] / (1.f + __expf(-a1[i][3]));
      *(float4*)&hl[m1 + i][tj * 4] = hv;
    }
    __syncthreads();

    for (int kk = 0; kk < 256; kk += 4) {
      float4 h4[4];
#pragma unroll
      for (int i = 0; i < 4; i++) h4[i] = *(const float4*)&hl[m2 + i][kk];
      int kg = cc * 256 + kk;
#pragma unroll
      for (int q = 0; q < 4; q++) {
        float4 wa = *(const float4*)&W2[(kg + q) * DM + d0];
        float4 wb = *(const float4*)&W2[(kg + q) * DM + d0 + 4];
#pragma unroll
        for (int i = 0; i < 4; i++) {
          float hq = (q == 0) ? h4[i].x : (q == 1) ? h4[i].y : (q == 2) ? h4[i].z : h4[i].w;
          acc2[i][0] += hq * wa.x;
          acc2[i][1] += hq * wa.y;
          acc2[i][2] += hq * wa.z;
          acc2[i][3] += hq * wa.w;
          acc2[i][4] += hq * wb.x;
          acc2[i][5] += hq * wb.y;
          acc2[i][6] += hq * wb.z;
          acc2[i][7] += hq * wb.w;
        }
      }
    }
    __syncthreads();
  }

#pragma unroll
  for (int i = 0; i < 4; i++) {
    float4 o1 = {acc2[i][0], acc2[i][1], acc2[i][2], acc2[i][3]};
    float4 o2 = {acc2[i][4], acc2[i][5], acc2[i][6], acc2[i][7]};
    *(float4*)&out[(e0 + m2 + i) * DM + d0] = o1;
    *(float4*)&out[(e0 + m2 + i) * DM + d0 + 4] = o2;
  }
}

// ----------------------------------------------------------------------------
extern "C" void kernel_launch(void* const* d_in, const int* in_sizes, int n_in,
                              void* d_out, int out_size, void* d_ws, size_t ws_size,
                              hipStream_t stream) {
  (void)in_sizes; (void)n_in; (void)out_size; (void)ws_size;
  const float* x      = (const float*)d_in[0];
  const float* y      = (const float*)d_in[1];
  const float* r      = (const float*)d_in[2];
  const int*   src    = (const int*)d_in[3];
  const int*   dst    = (const int*)d_in[4];
  const int*   tsrc   = (const int*)d_in[5];
  const int*   tdst   = (const int*)d_in[6];
  const float* W_src  = (const float*)d_in[7];
  const float* b_src  = (const float*)d_in[8];
  const float* W_dst  = (const float*)d_in[9];
  const float* b_dst  = (const float*)d_in[10];
  const float* W_edge = (const float*)d_in[11];
  const float* b_edge = (const float*)d_in[12];
  const float* attn   = (const float*)d_in[13];
  const float* W1     = (const float*)d_in[14];
  const float* b1     = (const float*)d_in[15];
  const float* W2     = (const float*)d_in[16];
  const float* b2     = (const float*)d_in[17];
  float* out = (float*)d_out;

  char* wsp = (char*)d_ws;
  auto alloc = [&](size_t bytes) -> char* {
    char* p = wsp;
    wsp += (bytes + 255) & ~(size_t)255;
    return p;
  };
  float* xs     = (float*)alloc((size_t)N_NODES * CH * 4);
  float* xd     = (float*)alloc((size_t)N_NODES * CH * 4);
  float* xij    = (float*)alloc((size_t)N_EDGES * CH * 4);
  float* rn     = (float*)alloc((size_t)N_EDGES * 3 * 4);
  float* logits = (float*)alloc((size_t)N_TRI * 4);
  int*   cnt    = (int*)alloc((size_t)N_EDGES * 4);
  int*   start  = (int*)alloc((size_t)(N_EDGES + 1) * 4);
  int*   cur    = (int*)alloc((size_t)N_EDGES * 4);
  int*   bsum   = (int*)alloc(1024 * 4);
  int*   sorted = (int*)alloc((size_t)N_TRI * 4);
  float* ftb    = (float*)alloc((size_t)N_EDGES * CH * 4);

  const int NB = (N_EDGES + 2047) / 2048;  // 79

  k_node_proj<<<N_NODES / 4, 256, 0, stream>>>(x, W_src, b_src, W_dst, b_dst, xs, xd);
  k_rnorm<<<N_EDGES / 256, 256, 0, stream>>>(r, rn);
  k_edge_proj<<<N_EDGES / 16, 256, 0, stream>>>(y, W_edge, b_edge, xs, xd, src, dst, xij);

  hipMemsetAsync(cnt, 0, (size_t)N_EDGES * 4, stream);
  k_hist<<<N_TRI / 256, 256, 0, stream>>>(tdst, cnt);
  k_scan_sum<<<NB, 256, 0, stream>>>(cnt, bsum, N_EDGES);
  k_scan_top<<<1, 64, 0, stream>>>(bsum, NB, &start[N_EDGES]);
  k_scan_apply<<<NB, 256, 0, stream>>>(cnt, bsum, start, cur, N_EDGES);
  k_scatter<<<N_TRI / 256, 256, 0, stream>>>(tdst, cur, sorted);

  k_logits<<<N_TRI / 4, 256, 0, stream>>>(rn, tsrc, tdst, xij, attn, logits);
  k_softmax_ft<<<N_EDGES / 4, 256, 0, stream>>>(start, sorted, logits, tsrc, xij, ftb);
  k_ffn<<<N_EDGES / 32, 256, 0, stream>>>(ftb, W1, b1, W2, b2, out);
}

// Round 2
// 1433.213 us; speedup vs baseline: 1.8951x; 1.8951x over previous
//
#include <hip/hip_runtime.h>

#define N_NODES 10000
#define N_EDGES 160000
#define N_TRI   1600000
#define DM      256
#define CH      64
#define HH      1024

typedef short bf16x8 __attribute__((ext_vector_type(8)));
typedef float f32x4  __attribute__((ext_vector_type(4)));

__device__ __forceinline__ unsigned short f2bf(float f) {
  unsigned int u = __float_as_uint(f);
  u += 0x7fff + ((u >> 16) & 1);   // RNE
  return (unsigned short)(u >> 16);
}

// ---------------------------------------------------------------- projections
__global__ __launch_bounds__(256) void k_node_proj(
    const float* __restrict__ x, const float* __restrict__ Ws, const float* __restrict__ bs,
    const float* __restrict__ Wd, const float* __restrict__ bd,
    float* __restrict__ xs, float* __restrict__ xd) {
  __shared__ float xl[4][DM];
  int tid = threadIdx.x;
  int n0 = blockIdx.x * 4;
  for (int i = tid; i < 4 * DM; i += 256) xl[i >> 8][i & 255] = x[n0 * DM + i];
  __syncthreads();
  int c = tid & 63, g = tid >> 6;
  float as = bs[c], ad = bd[c];
  for (int d = 0; d < DM; d++) {
    float xv = xl[g][d];
    as += xv * Ws[d * CH + c];
    ad += xv * Wd[d * CH + c];
  }
  int n = n0 + g;
  xs[n * CH + c] = as;
  xd[n * CH + c] = ad;
}

// ye = y@W_edge + b_edge, fused with gather-add -> xij
__global__ __launch_bounds__(256) void k_edge_proj(
    const float* __restrict__ y, const float* __restrict__ We, const float* __restrict__ be,
    const float* __restrict__ xs, const float* __restrict__ xd,
    const int* __restrict__ src, const int* __restrict__ dst,
    float* __restrict__ xij) {
  __shared__ float yl[16][DM];
  int tid = threadIdx.x;
  int e0 = blockIdx.x * 16;
  for (int i = tid; i < 16 * DM; i += 256) yl[i >> 8][i & 255] = y[e0 * DM + i];
  __syncthreads();
  int c = tid & 63, g = tid >> 6;
  float acc[4];
#pragma unroll
  for (int s = 0; s < 4; s++) acc[s] = be[c];
  for (int d = 0; d < DM; d += 4) {
    float w0 = We[(d + 0) * CH + c];
    float w1 = We[(d + 1) * CH + c];
    float w2 = We[(d + 2) * CH + c];
    float w3 = We[(d + 3) * CH + c];
#pragma unroll
    for (int s = 0; s < 4; s++) {
      const float4 yv = *(const float4*)&yl[g * 4 + s][d];
      acc[s] += yv.x * w0 + yv.y * w1 + yv.z * w2 + yv.w * w3;
    }
  }
#pragma unroll
  for (int s = 0; s < 4; s++) {
    int e = e0 + g * 4 + s;
    xij[e * CH + c] = acc[s] + xs[src[e] * CH + c] + xd[dst[e] * CH + c];
  }
}

// ---------------------------------------------------------------- rnorm
__global__ void k_rnorm(const float* __restrict__ r, float* __restrict__ rn) {
  int e = blockIdx.x * 256 + threadIdx.x;
  if (e >= N_EDGES) return;
  float a = r[e * 3 + 0], b = r[e * 3 + 1], c = r[e * 3 + 2];
  float inv = rsqrtf(a * a + b * b + c * c);
  rn[e * 3 + 0] = -a * inv;
  rn[e * 3 + 1] = -b * inv;
  rn[e * 3 + 2] = -c * inv;
}

// ---------------------------------------------------------------- counting sort by tdst
__global__ void k_hist(const int* __restrict__ tdst, int* __restrict__ cnt) {
  int t = blockIdx.x * 256 + threadIdx.x;
  if (t < N_TRI) atomicAdd(&cnt[tdst[t]], 1);
}

__global__ __launch_bounds__(256) void k_scan_sum(const int* __restrict__ cnt,
                                                  int* __restrict__ bsum, int n) {
  __shared__ int s[256];
  int b = blockIdx.x, tid = threadIdx.x;
  int tot = 0;
#pragma unroll
  for (int i = 0; i < 8; i++) {
    int idx = b * 2048 + i * 256 + tid;
    if (idx < n) tot += cnt[idx];
  }
  s[tid] = tot;
  __syncthreads();
  for (int off = 128; off > 0; off >>= 1) {
    if (tid < off) s[tid] += s[tid + off];
    __syncthreads();
  }
  if (tid == 0) bsum[b] = s[0];
}

__global__ void k_scan_top(int* __restrict__ bsum, int nb, int* __restrict__ start_last) {
  if (threadIdx.x == 0) {
    int run = 0;
    for (int i = 0; i < nb; i++) {
      int v = bsum[i];
      bsum[i] = run;
      run += v;
    }
    *start_last = run;  // == N_TRI
  }
}

__global__ __launch_bounds__(256) void k_scan_apply(const int* __restrict__ cnt,
                                                    const int* __restrict__ bsum,
                                                    int* __restrict__ start,
                                                    int* __restrict__ cur, int n) {
  __shared__ int s[256];
  int b = blockIdx.x, tid = threadIdx.x;
  int base = b * 2048 + tid * 8;
  int loc[8];
  int tot = 0;
#pragma unroll
  for (int i = 0; i < 8; i++) {
    int idx = base + i;
    int v = (idx < n) ? cnt[idx] : 0;
    loc[i] = tot;
    tot += v;
  }
  s[tid] = tot;
  __syncthreads();
  for (int off = 1; off < 256; off <<= 1) {
    int t2 = 0;
    if (tid >= off) t2 = s[tid - off];
    __syncthreads();
    if (tid >= off) s[tid] += t2;
    __syncthreads();
  }
  int excl = s[tid] - tot + bsum[b];
#pragma unroll
  for (int i = 0; i < 8; i++) {
    int idx = base + i;
    if (idx < n) {
      int v = excl + loc[i];
      start[idx] = v;
      cur[idx] = v;
    }
  }
}

__global__ void k_scatter(const int* __restrict__ tdst, int* __restrict__ cur,
                          int* __restrict__ sorted) {
  int t = blockIdx.x * 256 + threadIdx.x;
  if (t < N_TRI) {
    int p = atomicAdd(&cur[tdst[t]], 1);
    sorted[p] = t;
  }
}

// ---------------------------------------------------------------- triplet logits (one wave per triplet)
__global__ __launch_bounds__(256) void k_logits(
    const float* __restrict__ rn, const int* __restrict__ tsrc, const int* __restrict__ tdst,
    const float* __restrict__ xij, const float* __restrict__ attn,
    float* __restrict__ logits) {
  int tid = threadIdx.x;
  int t = blockIdx.x * 4 + (tid >> 6);
  int lane = tid & 63;
  int ts = tsrc[t], td = tdst[t];
  float ax = rn[ts * 3 + 0], ay = rn[ts * 3 + 1], az = rn[ts * 3 + 2];
  float bx = rn[td * 3 + 0], by = rn[td * 3 + 1], bz = rn[td * 3 + 2];
  float cosv = ax * bx + ay * by + az * bz;
  cosv = fminf(fmaxf(cosv, -1.0f + 1e-6f), 1.0f - 1e-6f);
  float theta = acosf(cosv);
  float z = __cosf(theta * (float)lane);
  float v = z + xij[ts * CH + lane] + xij[td * CH + lane];
  float sv = v / (1.0f + __expf(-v));
  float contrib = sv * attn[lane];
#pragma unroll
  for (int off = 32; off; off >>= 1) contrib += __shfl_xor(contrib, off);
  if (lane == 0) logits[t] = contrib;
}

// ---------------------------------------------------------------- segment softmax + weighted gather (one wave per edge)
// ft written directly as bf16 for the MFMA FFN.
__global__ __launch_bounds__(256) void k_softmax_ft(
    const int* __restrict__ start, const int* __restrict__ sorted,
    const float* __restrict__ logits, const int* __restrict__ tsrc,
    const float* __restrict__ xij, unsigned short* __restrict__ ft) {
  int tid = threadIdx.x;
  int e = blockIdx.x * 4 + (tid >> 6);
  int lane = tid & 63;
  int beg = start[e], end = start[e + 1];
  int deg = end - beg;
  float acc = 0.f;
  if (deg > 0) {
    if (deg <= 64) {
      int t = 0;
      float l = -1e30f;
      int ts_ = 0;
      if (lane < deg) {
        t = sorted[beg + lane];
        l = logits[t];
        ts_ = tsrc[t];
      }
      float mx = l;
#pragma unroll
      for (int off = 32; off; off >>= 1) mx = fmaxf(mx, __shfl_xor(mx, off));
      float ex = (lane < deg) ? __expf(l - mx) : 0.f;
      float den = ex;
#pragma unroll
      for (int off = 32; off; off >>= 1) den += __shfl_xor(den, off);
      float p = ex / den;
      for (int i = 0; i < deg; i++) {
        int tsi = __shfl(ts_, i);
        float ai = __shfl(p, i);
        acc += ai * xij[tsi * CH + lane];
      }
    } else {
      float mx = -1e30f;
      for (int i = lane; i < deg; i += 64) mx = fmaxf(mx, logits[sorted[beg + i]]);
#pragma unroll
      for (int off = 32; off; off >>= 1) mx = fmaxf(mx, __shfl_xor(mx, off));
      float den = 0.f;
      for (int i = lane; i < deg; i += 64) den += __expf(logits[sorted[beg + i]] - mx);
#pragma unroll
      for (int off = 32; off; off >>= 1) den += __shfl_xor(den, off);
      for (int i = 0; i < deg; i++) {
        int tt = sorted[beg + i];
        float ai = __expf(logits[tt] - mx) / den;
        acc += ai * xij[tsrc[tt] * CH + lane];
      }
    }
  }
  ft[e * CH + lane] = f2bf(acc);
}

// ---------------------------------------------------------------- weight prep: fp32 -> bf16, transposed (n-major, k contiguous)
__global__ __launch_bounds__(256) void k_prep_w1t(const float* __restrict__ W1,
                                                  unsigned short* __restrict__ W1T) {
  int idx = blockIdx.x * 256 + threadIdx.x;   // idx = n*64 + k, n<1024, k<64
  int n = idx >> 6, k = idx & 63;
  W1T[idx] = f2bf(W1[k * HH + n]);
}

__global__ __launch_bounds__(256) void k_prep_w2t(const float* __restrict__ W2,
                                                  unsigned short* __restrict__ W2T) {
  int idx = blockIdx.x * 256 + threadIdx.x;   // idx = n*1024 + k, n<256, k<1024
  int n = idx >> 10, k = idx & 1023;
  W2T[idx] = f2bf(W2[k * DM + n]);
}

// ---------------------------------------------------------------- fused MFMA FFN
// out = silu(ft@W1+b1)@W2 + b2.  64 edges/block, 4 waves; each wave owns a
// 64x64 slice of the 64x256 output.  H processed in 16 chunks of 64 with an
// LDS round-trip for the hidden activations (C-layout -> A-layout).
#define HL_STRIDE 72   // bf16 elems; 144 B rows: 16B-aligned, 2-way bank alias only
__global__ __launch_bounds__(256) void k_ffn_mfma(
    const unsigned short* __restrict__ ft, const unsigned short* __restrict__ W1T,
    const float* __restrict__ b1, const unsigned short* __restrict__ W2T,
    const float* __restrict__ b2, float* __restrict__ out) {
  __shared__ unsigned short ftl[64 * 64];            // 8 KB
  __shared__ unsigned short hl[2][64 * HL_STRIDE];   // 2 x 9 KB
  int tid = threadIdx.x;
  int wave = tid >> 6, lane = tid & 63;
  int l16 = lane & 15, lq = lane >> 4;
  int e0 = blockIdx.x * 64;

  // stage ft tile (64x64 bf16, row-major)
  {
    const uint* g = (const uint*)(ft + (size_t)e0 * CH);
    uint* s = (uint*)ftl;
    for (int i = tid; i < 64 * 32; i += 256) s[i] = g[i];
  }
  __syncthreads();

  // ft A-fragments: [m-tile][k-step], reused for all 16 chunks
  bf16x8 aft[4][2];
#pragma unroll
  for (int mt = 0; mt < 4; mt++)
#pragma unroll
    for (int s = 0; s < 2; s++)
      aft[mt][s] = *(const bf16x8*)&ftl[(mt * 16 + l16) * 64 + s * 32 + lq * 8];

  f32x4 acc[4][4];
#pragma unroll
  for (int mt = 0; mt < 4; mt++)
#pragma unroll
    for (int nt = 0; nt < 4; nt++) acc[mt][nt] = (f32x4){0.f, 0.f, 0.f, 0.f};

  for (int cc = 0; cc < 16; cc++) {
    int p = cc & 1;
    // ---- GEMM1: this wave computes h[:, cc*64 + wave*16 .. +16]
    {
      int ncol = cc * 64 + wave * 16 + l16;           // hidden col for B frag
      const unsigned short* wp = &W1T[ncol * 64 + lq * 8];
      bf16x8 bw0 = *(const bf16x8*)wp;
      bf16x8 bw1 = *(const bf16x8*)(wp + 32);
      float b1v = b1[ncol];
#pragma unroll
      for (int mt = 0; mt < 4; mt++) {
        f32x4 h = (f32x4){0.f, 0.f, 0.f, 0.f};
        h = __builtin_amdgcn_mfma_f32_16x16x32_bf16(aft[mt][0], bw0, h, 0, 0, 0);
        h = __builtin_amdgcn_mfma_f32_16x16x32_bf16(aft[mt][1], bw1, h, 0, 0, 0);
#pragma unroll
        for (int r = 0; r < 4; r++) {
          float v = h[r] + b1v;
          float sv = v / (1.f + __expf(-v));
          hl[p][(mt * 16 + lq * 4 + r) * HL_STRIDE + wave * 16 + l16] = f2bf(sv);
        }
      }
    }
    __syncthreads();
    // ---- GEMM2: acc[64x64 slice] += h(64x64) @ W2[cc*64.., wave*64..]
#pragma unroll
    for (int nt = 0; nt < 4; nt++) {
      const unsigned short* wp =
          &W2T[(size_t)(wave * 64 + nt * 16 + l16) * HH + cc * 64 + lq * 8];
      bf16x8 b0 = *(const bf16x8*)wp;
      bf16x8 b1f = *(const bf16x8*)(wp + 32);
#pragma unroll
      for (int mt = 0; mt < 4; mt++) {
        bf16x8 a0 = *(const bf16x8*)&hl[p][(mt * 16 + l16) * HL_STRIDE + lq * 8];
        bf16x8 a1 = *(const bf16x8*)&hl[p][(mt * 16 + l16) * HL_STRIDE + 32 + lq * 8];
        acc[mt][nt] = __builtin_amdgcn_mfma_f32_16x16x32_bf16(a0, b0, acc[mt][nt], 0, 0, 0);
        acc[mt][nt] = __builtin_amdgcn_mfma_f32_16x16x32_bf16(a1, b1f, acc[mt][nt], 0, 0, 0);
      }
    }
  }

  // epilogue: + b2, fp32 store
#pragma unroll
  for (int nt = 0; nt < 4; nt++) {
    int col = wave * 64 + nt * 16 + l16;
    float b2v = b2[col];
#pragma unroll
    for (int mt = 0; mt < 4; mt++) {
      int row = e0 + mt * 16 + lq * 4;
#pragma unroll
      for (int r = 0; r < 4; r++)
        out[(size_t)(row + r) * DM + col] = acc[mt][nt][r] + b2v;
    }
  }
}

// ----------------------------------------------------------------------------
extern "C" void kernel_launch(void* const* d_in, const int* in_sizes, int n_in,
                              void* d_out, int out_size, void* d_ws, size_t ws_size,
                              hipStream_t stream) {
  (void)in_sizes; (void)n_in; (void)out_size; (void)ws_size;
  const float* x      = (const float*)d_in[0];
  const float* y      = (const float*)d_in[1];
  const float* r      = (const float*)d_in[2];
  const int*   src    = (const int*)d_in[3];
  const int*   dst    = (const int*)d_in[4];
  const int*   tsrc   = (const int*)d_in[5];
  const int*   tdst   = (const int*)d_in[6];
  const float* W_src  = (const float*)d_in[7];
  const float* b_src  = (const float*)d_in[8];
  const float* W_dst  = (const float*)d_in[9];
  const float* b_dst  = (const float*)d_in[10];
  const float* W_edge = (const float*)d_in[11];
  const float* b_edge = (const float*)d_in[12];
  const float* attn   = (const float*)d_in[13];
  const float* W1     = (const float*)d_in[14];
  const float* b1     = (const float*)d_in[15];
  const float* W2     = (const float*)d_in[16];
  const float* b2     = (const float*)d_in[17];
  float* out = (float*)d_out;

  char* wsp = (char*)d_ws;
  auto alloc = [&](size_t bytes) -> char* {
    char* p = wsp;
    wsp += (bytes + 255) & ~(size_t)255;
    return p;
  };
  float* xs     = (float*)alloc((size_t)N_NODES * CH * 4);
  float* xd     = (float*)alloc((size_t)N_NODES * CH * 4);
  float* xij    = (float*)alloc((size_t)N_EDGES * CH * 4);
  float* rn     = (float*)alloc((size_t)N_EDGES * 3 * 4);
  float* logits = (float*)alloc((size_t)N_TRI * 4);
  int*   cnt    = (int*)alloc((size_t)N_EDGES * 4);
  int*   start  = (int*)alloc((size_t)(N_EDGES + 1) * 4);
  int*   cur    = (int*)alloc((size_t)N_EDGES * 4);
  int*   bsum   = (int*)alloc(1024 * 4);
  int*   sorted = (int*)alloc((size_t)N_TRI * 4);
  unsigned short* ftb = (unsigned short*)alloc((size_t)N_EDGES * CH * 2);
  unsigned short* W1T = (unsigned short*)alloc((size_t)CH * HH * 2);
  unsigned short* W2T = (unsigned short*)alloc((size_t)HH * DM * 2);

  const int NB = (N_EDGES + 2047) / 2048;  // 79

  // weight prep (E-independent, tiny)
  k_prep_w1t<<<(CH * HH) / 256, 256, 0, stream>>>(W1, W1T);
  k_prep_w2t<<<(HH * DM) / 256, 256, 0, stream>>>(W2, W2T);

  k_node_proj<<<N_NODES / 4, 256, 0, stream>>>(x, W_src, b_src, W_dst, b_dst, xs, xd);
  k_rnorm<<<N_EDGES / 256, 256, 0, stream>>>(r, rn);
  k_edge_proj<<<N_EDGES / 16, 256, 0, stream>>>(y, W_edge, b_edge, xs, xd, src, dst, xij);

  hipMemsetAsync(cnt, 0, (size_t)N_EDGES * 4, stream);
  k_hist<<<N_TRI / 256, 256, 0, stream>>>(tdst, cnt);
  k_scan_sum<<<NB, 256, 0, stream>>>(cnt, bsum, N_EDGES);
  k_scan_top<<<1, 64, 0, stream>>>(bsum, NB, &start[N_EDGES]);
  k_scan_apply<<<NB, 256, 0, stream>>>(cnt, bsum, start, cur, N_EDGES);
  k_scatter<<<N_TRI / 256, 256, 0, stream>>>(tdst, cur, sorted);

  k_logits<<<N_TRI / 4, 256, 0, stream>>>(rn, tsrc, tdst, xij, attn, logits);
  k_softmax_ft<<<N_EDGES / 4, 256, 0, stream>>>(start, sorted, logits, tsrc, xij, ftb);
  k_ffn_mfma<<<N_EDGES / 64, 256, 0, stream>>>(ftb, W1T, b1, W2T, b2, out);
}

// Round 3
// 1391.212 us; speedup vs baseline: 1.9524x; 1.0302x over previous
//
#include <hip/hip_runtime.h>

#define N_NODES 10000
#define N_EDGES 160000
#define N_TRI   1600000
#define DM      256
#define CH      64
#define HH      1024

typedef short bf16x8 __attribute__((ext_vector_type(8)));
typedef float f32x4  __attribute__((ext_vector_type(4)));

__device__ __forceinline__ unsigned short f2bf(float f) {
  unsigned int u = __float_as_uint(f);
  u += 0x7fff + ((u >> 16) & 1);   // RNE
  return (unsigned short)(u >> 16);
}

// ---------------------------------------------------------------- projections
__global__ __launch_bounds__(256) void k_node_proj(
    const float* __restrict__ x, const float* __restrict__ Ws, const float* __restrict__ bs,
    const float* __restrict__ Wd, const float* __restrict__ bd,
    float* __restrict__ xs, float* __restrict__ xd) {
  __shared__ float xl[4][DM];
  int tid = threadIdx.x;
  int n0 = blockIdx.x * 4;
  for (int i = tid; i < 4 * DM; i += 256) xl[i >> 8][i & 255] = x[n0 * DM + i];
  __syncthreads();
  int c = tid & 63, g = tid >> 6;
  float as = bs[c], ad = bd[c];
  for (int d = 0; d < DM; d++) {
    float xv = xl[g][d];
    as += xv * Ws[d * CH + c];
    ad += xv * Wd[d * CH + c];
  }
  int n = n0 + g;
  xs[n * CH + c] = as;
  xd[n * CH + c] = ad;
}

// ye = y@W_edge + b_edge, fused with gather-add -> xij
__global__ __launch_bounds__(256) void k_edge_proj(
    const float* __restrict__ y, const float* __restrict__ We, const float* __restrict__ be,
    const float* __restrict__ xs, const float* __restrict__ xd,
    const int* __restrict__ src, const int* __restrict__ dst,
    float* __restrict__ xij) {
  __shared__ float yl[16][DM];
  int tid = threadIdx.x;
  int e0 = blockIdx.x * 16;
  for (int i = tid; i < 16 * DM; i += 256) yl[i >> 8][i & 255] = y[e0 * DM + i];
  __syncthreads();
  int c = tid & 63, g = tid >> 6;
  float acc[4];
#pragma unroll
  for (int s = 0; s < 4; s++) acc[s] = be[c];
  for (int d = 0; d < DM; d += 4) {
    float w0 = We[(d + 0) * CH + c];
    float w1 = We[(d + 1) * CH + c];
    float w2 = We[(d + 2) * CH + c];
    float w3 = We[(d + 3) * CH + c];
#pragma unroll
    for (int s = 0; s < 4; s++) {
      const float4 yv = *(const float4*)&yl[g * 4 + s][d];
      acc[s] += yv.x * w0 + yv.y * w1 + yv.z * w2 + yv.w * w3;
    }
  }
#pragma unroll
  for (int s = 0; s < 4; s++) {
    int e = e0 + g * 4 + s;
    xij[e * CH + c] = acc[s] + xs[src[e] * CH + c] + xd[dst[e] * CH + c];
  }
}

// ---------------------------------------------------------------- rnorm (padded float4 for 1-inst gathers)
__global__ void k_rnorm(const float* __restrict__ r, float4* __restrict__ rn4) {
  int e = blockIdx.x * 256 + threadIdx.x;
  if (e >= N_EDGES) return;
  float a = r[e * 3 + 0], b = r[e * 3 + 1], c = r[e * 3 + 2];
  float inv = rsqrtf(a * a + b * b + c * c);
  rn4[e] = (float4){-a * inv, -b * inv, -c * inv, 0.f};
}

// ---------------------------------------------------------------- per-triplet theta (hoists acos + rn gathers out of the per-lane path)
__global__ __launch_bounds__(256) void k_theta(
    const float4* __restrict__ rn4, const int* __restrict__ tsrc, const int* __restrict__ tdst,
    float* __restrict__ theta) {
  int t = blockIdx.x * 256 + threadIdx.x;
  if (t >= N_TRI) return;
  float4 a = rn4[tsrc[t]];
  float4 b = rn4[tdst[t]];
  float c = a.x * b.x + a.y * b.y + a.z * b.z;
  c = fminf(fmaxf(c, -1.0f + 1e-6f), 1.0f - 1e-6f);
  theta[t] = acosf(c);
}

// ---------------------------------------------------------------- counting sort by tdst
__global__ void k_hist(const int* __restrict__ tdst, int* __restrict__ cnt) {
  int t = blockIdx.x * 256 + threadIdx.x;
  if (t < N_TRI) atomicAdd(&cnt[tdst[t]], 1);
}

__global__ __launch_bounds__(256) void k_scan_sum(const int* __restrict__ cnt,
                                                  int* __restrict__ bsum, int n) {
  __shared__ int s[256];
  int b = blockIdx.x, tid = threadIdx.x;
  int tot = 0;
#pragma unroll
  for (int i = 0; i < 8; i++) {
    int idx = b * 2048 + i * 256 + tid;
    if (idx < n) tot += cnt[idx];
  }
  s[tid] = tot;
  __syncthreads();
  for (int off = 128; off > 0; off >>= 1) {
    if (tid < off) s[tid] += s[tid + off];
    __syncthreads();
  }
  if (tid == 0) bsum[b] = s[0];
}

__global__ void k_scan_top(int* __restrict__ bsum, int nb, int* __restrict__ start_last) {
  if (threadIdx.x == 0) {
    int run = 0;
    for (int i = 0; i < nb; i++) {
      int v = bsum[i];
      bsum[i] = run;
      run += v;
    }
    *start_last = run;  // == N_TRI
  }
}

__global__ __launch_bounds__(256) void k_scan_apply(const int* __restrict__ cnt,
                                                    const int* __restrict__ bsum,
                                                    int* __restrict__ start,
                                                    int* __restrict__ cur, int n) {
  __shared__ int s[256];
  int b = blockIdx.x, tid = threadIdx.x;
  int base = b * 2048 + tid * 8;
  int loc[8];
  int tot = 0;
#pragma unroll
  for (int i = 0; i < 8; i++) {
    int idx = base + i;
    int v = (idx < n) ? cnt[idx] : 0;
    loc[i] = tot;
    tot += v;
  }
  s[tid] = tot;
  __syncthreads();
  for (int off = 1; off < 256; off <<= 1) {
    int t2 = 0;
    if (tid >= off) t2 = s[tid - off];
    __syncthreads();
    if (tid >= off) s[tid] += t2;
    __syncthreads();
  }
  int excl = s[tid] - tot + bsum[b];
#pragma unroll
  for (int i = 0; i < 8; i++) {
    int idx = base + i;
    if (idx < n) {
      int v = excl + loc[i];
      start[idx] = v;
      cur[idx] = v;
    }
  }
}

__global__ void k_scatter(const int* __restrict__ tdst, int* __restrict__ cur,
                          int* __restrict__ sorted) {
  int t = blockIdx.x * 256 + threadIdx.x;
  if (t < N_TRI) {
    int p = atomicAdd(&cur[tdst[t]], 1);
    sorted[p] = t;
  }
}

// ---------------------------------------------------------------- triplet logits (one wave per triplet; theta precomputed)
__global__ __launch_bounds__(256) void k_logits(
    const float* __restrict__ theta, const int* __restrict__ tsrc, const int* __restrict__ tdst,
    const float* __restrict__ xij, const float* __restrict__ attn,
    float* __restrict__ logits) {
  int tid = threadIdx.x;
  int t = blockIdx.x * 4 + (tid >> 6);
  int lane = tid & 63;
  float th = theta[t];
  int ts = tsrc[t], td = tdst[t];
  float z = __cosf(th * (float)lane);
  float v = z + xij[ts * CH + lane] + xij[td * CH + lane];
  float sv = v / (1.0f + __expf(-v));
  float contrib = sv * attn[lane];
#pragma unroll
  for (int off = 32; off; off >>= 1) contrib += __shfl_xor(contrib, off);
  if (lane == 0) logits[t] = contrib;
}

// ---------------------------------------------------------------- segment softmax + weighted gather (one wave per edge)
// ft written directly as bf16 for the MFMA FFN.
__global__ __launch_bounds__(256) void k_softmax_ft(
    const int* __restrict__ start, const int* __restrict__ sorted,
    const float* __restrict__ logits, const int* __restrict__ tsrc,
    const float* __restrict__ xij, unsigned short* __restrict__ ft) {
  int tid = threadIdx.x;
  int e = blockIdx.x * 4 + (tid >> 6);
  int lane = tid & 63;
  int beg = start[e], end = start[e + 1];
  int deg = end - beg;
  float acc = 0.f;
  if (deg > 0) {
    if (deg <= 64) {
      int t = 0;
      float l = -1e30f;
      int ts_ = 0;
      if (lane < deg) {
        t = sorted[beg + lane];
        l = logits[t];
        ts_ = tsrc[t];
      }
      float mx = l;
#pragma unroll
      for (int off = 32; off; off >>= 1) mx = fmaxf(mx, __shfl_xor(mx, off));
      float ex = (lane < deg) ? __expf(l - mx) : 0.f;
      float den = ex;
#pragma unroll
      for (int off = 32; off; off >>= 1) den += __shfl_xor(den, off);
      float p = ex / den;
      for (int i = 0; i < deg; i++) {
        int tsi = __shfl(ts_, i);
        float ai = __shfl(p, i);
        acc += ai * xij[tsi * CH + lane];
      }
    } else {
      float mx = -1e30f;
      for (int i = lane; i < deg; i += 64) mx = fmaxf(mx, logits[sorted[beg + i]]);
#pragma unroll
      for (int off = 32; off; off >>= 1) mx = fmaxf(mx, __shfl_xor(mx, off));
      float den = 0.f;
      for (int i = lane; i < deg; i += 64) den += __expf(logits[sorted[beg + i]] - mx);
#pragma unroll
      for (int off = 32; off; off >>= 1) den += __shfl_xor(den, off);
      for (int i = 0; i < deg; i++) {
        int tt = sorted[beg + i];
        float ai = __expf(logits[tt] - mx) / den;
        acc += ai * xij[tsrc[tt] * CH + lane];
      }
    }
  }
  ft[e * CH + lane] = f2bf(acc);
}

// ---------------------------------------------------------------- weight prep: fp32 -> bf16, transposed (n-major, k contiguous)
__global__ __launch_bounds__(256) void k_prep_w1t(const float* __restrict__ W1,
                                                  unsigned short* __restrict__ W1T) {
  int idx = blockIdx.x * 256 + threadIdx.x;   // idx = n*64 + k, n<1024, k<64
  int n = idx >> 6, k = idx & 63;
  W1T[idx] = f2bf(W1[k * HH + n]);
}

__global__ __launch_bounds__(256) void k_prep_w2t(const float* __restrict__ W2,
                                                  unsigned short* __restrict__ W2T) {
  int idx = blockIdx.x * 256 + threadIdx.x;   // idx = n*1024 + k, n<256, k<1024
  int n = idx >> 10, k = idx & 1023;
  W2T[idx] = f2bf(W2[k * DM + n]);
}

// ---------------------------------------------------------------- fused MFMA FFN
// out = silu(ft@W1+b1)@W2 + b2.  64 edges/block, 4 waves; each wave owns a
// 64x64 slice of the 64x256 output.  H processed in 16 chunks of 64 with an
// LDS round-trip for the hidden activations (C-layout -> A-layout).
#define HL_STRIDE 72   // bf16 elems; 144 B rows: 16B-aligned, 2-way bank alias only
__global__ __launch_bounds__(256) void k_ffn_mfma(
    const unsigned short* __restrict__ ft, const unsigned short* __restrict__ W1T,
    const float* __restrict__ b1, const unsigned short* __restrict__ W2T,
    const float* __restrict__ b2, float* __restrict__ out) {
  __shared__ unsigned short ftl[64 * 64];            // 8 KB
  __shared__ unsigned short hl[2][64 * HL_STRIDE];   // 2 x 9 KB
  int tid = threadIdx.x;
  int wave = tid >> 6, lane = tid & 63;
  int l16 = lane & 15, lq = lane >> 4;
  int e0 = blockIdx.x * 64;

  // stage ft tile (64x64 bf16, row-major)
  {
    const uint* g = (const uint*)(ft + (size_t)e0 * CH);
    uint* s = (uint*)ftl;
    for (int i = tid; i < 64 * 32; i += 256) s[i] = g[i];
  }
  __syncthreads();

  // ft A-fragments: [m-tile][k-step], reused for all 16 chunks
  bf16x8 aft[4][2];
#pragma unroll
  for (int mt = 0; mt < 4; mt++)
#pragma unroll
    for (int s = 0; s < 2; s++)
      aft[mt][s] = *(const bf16x8*)&ftl[(mt * 16 + l16) * 64 + s * 32 + lq * 8];

  f32x4 acc[4][4];
#pragma unroll
  for (int mt = 0; mt < 4; mt++)
#pragma unroll
    for (int nt = 0; nt < 4; nt++) acc[mt][nt] = (f32x4){0.f, 0.f, 0.f, 0.f};

  for (int cc = 0; cc < 16; cc++) {
    int p = cc & 1;
    // ---- GEMM1: this wave computes h[:, cc*64 + wave*16 .. +16]
    {
      int ncol = cc * 64 + wave * 16 + l16;           // hidden col for B frag
      const unsigned short* wp = &W1T[ncol * 64 + lq * 8];
      bf16x8 bw0 = *(const bf16x8*)wp;
      bf16x8 bw1 = *(const bf16x8*)(wp + 32);
      float b1v = b1[ncol];
#pragma unroll
      for (int mt = 0; mt < 4; mt++) {
        f32x4 h = (f32x4){0.f, 0.f, 0.f, 0.f};
        h = __builtin_amdgcn_mfma_f32_16x16x32_bf16(aft[mt][0], bw0, h, 0, 0, 0);
        h = __builtin_amdgcn_mfma_f32_16x16x32_bf16(aft[mt][1], bw1, h, 0, 0, 0);
#pragma unroll
        for (int r = 0; r < 4; r++) {
          float v = h[r] + b1v;
          float sv = v / (1.f + __expf(-v));
          hl[p][(mt * 16 + lq * 4 + r) * HL_STRIDE + wave * 16 + l16] = f2bf(sv);
        }
      }
    }
    __syncthreads();
    // ---- GEMM2: acc[64x64 slice] += h(64x64) @ W2[cc*64.., wave*64..]
#pragma unroll
    for (int nt = 0; nt < 4; nt++) {
      const unsigned short* wp =
          &W2T[(size_t)(wave * 64 + nt * 16 + l16) * HH + cc * 64 + lq * 8];
      bf16x8 b0 = *(const bf16x8*)wp;
      bf16x8 b1f = *(const bf16x8*)(wp + 32);
#pragma unroll
      for (int mt = 0; mt < 4; mt++) {
        bf16x8 a0 = *(const bf16x8*)&hl[p][(mt * 16 + l16) * HL_STRIDE + lq * 8];
        bf16x8 a1 = *(const bf16x8*)&hl[p][(mt * 16 + l16) * HL_STRIDE + 32 + lq * 8];
        acc[mt][nt] = __builtin_amdgcn_mfma_f32_16x16x32_bf16(a0, b0, acc[mt][nt], 0, 0, 0);
        acc[mt][nt] = __builtin_amdgcn_mfma_f32_16x16x32_bf16(a1, b1f, acc[mt][nt], 0, 0, 0);
      }
    }
  }

  // epilogue: + b2, fp32 store
#pragma unroll
  for (int nt = 0; nt < 4; nt++) {
    int col = wave * 64 + nt * 16 + l16;
    float b2v = b2[col];
#pragma unroll
    for (int mt = 0; mt < 4; mt++) {
      int row = e0 + mt * 16 + lq * 4;
#pragma unroll
      for (int r = 0; r < 4; r++)
        out[(size_t)(row + r) * DM + col] = acc[mt][nt][r] + b2v;
    }
  }
}

// ----------------------------------------------------------------------------
extern "C" void kernel_launch(void* const* d_in, const int* in_sizes, int n_in,
                              void* d_out, int out_size, void* d_ws, size_t ws_size,
                              hipStream_t stream) {
  (void)in_sizes; (void)n_in; (void)out_size; (void)ws_size;
  const float* x      = (const float*)d_in[0];
  const float* y      = (const float*)d_in[1];
  const float* r      = (const float*)d_in[2];
  const int*   src    = (const int*)d_in[3];
  const int*   dst    = (const int*)d_in[4];
  const int*   tsrc   = (const int*)d_in[5];
  const int*   tdst   = (const int*)d_in[6];
  const float* W_src  = (const float*)d_in[7];
  const float* b_src  = (const float*)d_in[8];
  const float* W_dst  = (const float*)d_in[9];
  const float* b_dst  = (const float*)d_in[10];
  const float* W_edge = (const float*)d_in[11];
  const float* b_edge = (const float*)d_in[12];
  const float* attn   = (const float*)d_in[13];
  const float* W1     = (const float*)d_in[14];
  const float* b1     = (const float*)d_in[15];
  const float* W2     = (const float*)d_in[16];
  const float* b2     = (const float*)d_in[17];
  float* out = (float*)d_out;

  char* wsp = (char*)d_ws;
  auto alloc = [&](size_t bytes) -> char* {
    char* p = wsp;
    wsp += (bytes + 255) & ~(size_t)255;
    return p;
  };
  float* xs     = (float*)alloc((size_t)N_NODES * CH * 4);
  float* xd     = (float*)alloc((size_t)N_NODES * CH * 4);
  float* xij    = (float*)alloc((size_t)N_EDGES * CH * 4);
  float4* rn4   = (float4*)alloc((size_t)N_EDGES * 16);
  float* theta  = (float*)alloc((size_t)N_TRI * 4);
  float* logits = (float*)alloc((size_t)N_TRI * 4);
  int*   cnt    = (int*)alloc((size_t)N_EDGES * 4);
  int*   start  = (int*)alloc((size_t)(N_EDGES + 1) * 4);
  int*   cur    = (int*)alloc((size_t)N_EDGES * 4);
  int*   bsum   = (int*)alloc(1024 * 4);
  int*   sorted = (int*)alloc((size_t)N_TRI * 4);
  unsigned short* ftb = (unsigned short*)alloc((size_t)N_EDGES * CH * 2);
  unsigned short* W1T = (unsigned short*)alloc((size_t)CH * HH * 2);
  unsigned short* W2T = (unsigned short*)alloc((size_t)HH * DM * 2);

  const int NB = (N_EDGES + 2047) / 2048;  // 79

  // weight prep (E-independent, tiny)
  k_prep_w1t<<<(CH * HH) / 256, 256, 0, stream>>>(W1, W1T);
  k_prep_w2t<<<(HH * DM) / 256, 256, 0, stream>>>(W2, W2T);

  k_node_proj<<<N_NODES / 4, 256, 0, stream>>>(x, W_src, b_src, W_dst, b_dst, xs, xd);
  k_rnorm<<<N_EDGES / 256, 256, 0, stream>>>(r, rn4);
  k_edge_proj<<<N_EDGES / 16, 256, 0, stream>>>(y, W_edge, b_edge, xs, xd, src, dst, xij);
  k_theta<<<N_TRI / 256, 256, 0, stream>>>(rn4, tsrc, tdst, theta);

  hipMemsetAsync(cnt, 0, (size_t)N_EDGES * 4, stream);
  k_hist<<<N_TRI / 256, 256, 0, stream>>>(tdst, cnt);
  k_scan_sum<<<NB, 256, 0, stream>>>(cnt, bsum, N_EDGES);
  k_scan_top<<<1, 64, 0, stream>>>(bsum, NB, &start[N_EDGES]);
  k_scan_apply<<<NB, 256, 0, stream>>>(cnt, bsum, start, cur, N_EDGES);
  k_scatter<<<N_TRI / 256, 256, 0, stream>>>(tdst, cur, sorted);

  k_logits<<<N_TRI / 4, 256, 0, stream>>>(theta, tsrc, tdst, xij, attn, logits);
  k_softmax_ft<<<N_EDGES / 4, 256, 0, stream>>>(start, sorted, logits, tsrc, xij, ftb);
  k_ffn_mfma<<<N_EDGES / 64, 256, 0, stream>>>(ftb, W1T, b1, W2T, b2, out);
}